// Round 6
// baseline (1087.622 us; speedup 1.0000x reference)
//
#include <hip/hip_runtime.h>
#include <cstdint>

#define NFEAT 512
#define NHID 256
#define NCLASS 64
#define CH 32
#define WBINS 8192

typedef __attribute__((ext_vector_type(8))) short bf16x8;
typedef __attribute__((ext_vector_type(4))) float f32x4;

__device__ __forceinline__ unsigned short f2bf(float f) {
  unsigned u = __builtin_bit_cast(unsigned, f);
  u = (u + 0x7FFF + ((u >> 16) & 1)) >> 16;   // RNE
  return (unsigned short)u;
}
__device__ __forceinline__ float bfu(unsigned short u) {
  return __builtin_bit_cast(float, (unsigned)u << 16);
}

// ---------------- weight conversion (fused, once per call, tiny)
__global__ __launch_bounds__(256)
void convert_w12(const float* __restrict__ W1, short* __restrict__ W1T,
                 const float* __restrict__ W2, short* __restrict__ W2T) {
  const int idx = blockIdx.x * 256 + threadIdx.x;
  if (idx < 512 * 256) {
    const int k = idx >> 8, n = idx & 255;
    W1T[n * 512 + k] = (short)f2bf(W1[idx]);
  }
  if (idx < 256 * 64) {
    const int k = idx >> 6, n = idx & 63;
    W2T[n * 256 + k] = (short)f2bf(W2[idx]);
  }
}

// ---------------- GEMM1: C[M][256](bf16) = A[M][512](fp32) @ W1, B = W1T [256][512] bf16
__global__ __launch_bounds__(256)
void gemm1_mfma(const float* __restrict__ A, const short* __restrict__ BT,
                unsigned short* __restrict__ C, int M) {
  __shared__ short As[128 * 32];            // 8 KB
  const int t    = threadIdx.x;
  const int w    = t >> 6;
  const int lane = t & 63;
  const int lr   = lane & 15;
  const int g    = lane >> 4;
  const int bm   = blockIdx.x * 128;

  f32x4 acc[8][4] = {};

  for (int k0 = 0; k0 < NFEAT; k0 += 32) {
#pragma unroll
    for (int p = 0; p < 2; ++p) {
      const int gran = p * 256 + t;
      const int row  = gran >> 2;
      const int kc   = (gran & 3) << 3;
      const int grow = bm + row;
      float4 f0 = make_float4(0.f, 0.f, 0.f, 0.f), f1 = f0;
      if (grow < M) {
        const float* src = A + (size_t)grow * NFEAT + k0 + kc;
        f0 = *(const float4*)(src);
        f1 = *(const float4*)(src + 4);
      }
      union { bf16x8 v; unsigned short u[8]; } pk;
      pk.u[0] = f2bf(f0.x); pk.u[1] = f2bf(f0.y); pk.u[2] = f2bf(f0.z); pk.u[3] = f2bf(f0.w);
      pk.u[4] = f2bf(f1.x); pk.u[5] = f2bf(f1.y); pk.u[6] = f2bf(f1.z); pk.u[7] = f2bf(f1.w);
      *(bf16x8*)(&As[gran * 8]) = pk.v;
    }
    __syncthreads();

    bf16x8 bfr[4];
#pragma unroll
    for (int n = 0; n < 4; ++n) {
      const int col = w * 64 + n * 16 + lr;
      bfr[n] = *(const bf16x8*)(BT + (size_t)col * NFEAT + k0 + g * 8);
    }
#pragma unroll
    for (int m = 0; m < 8; ++m) {
      const bf16x8 af = *(const bf16x8*)(&As[(m * 16 + lr) * 32 + g * 8]);
#pragma unroll
      for (int n = 0; n < 4; ++n)
        acc[m][n] = __builtin_amdgcn_mfma_f32_16x16x32_bf16(af, bfr[n], acc[m][n], 0, 0, 0);
    }
    __syncthreads();
  }

#pragma unroll
  for (int m = 0; m < 8; ++m) {
#pragma unroll
    for (int r = 0; r < 4; ++r) {
      const int row = bm + m * 16 + g * 4 + r;
      if (row < M) {
#pragma unroll
        for (int n = 0; n < 4; ++n) {
          const int col = w * 64 + n * 16 + lr;
          C[(size_t)row * NHID + col] = f2bf(acc[m][n][r]);
        }
      }
    }
  }
}

// ---------------- GEMM2: C[M][64](bf16) = A[M][256](bf16) @ W2, B = W2T [64][256] bf16
__global__ __launch_bounds__(256)
void gemm2_mfma(const unsigned short* __restrict__ A, const short* __restrict__ BT,
                unsigned short* __restrict__ C, int M) {
  __shared__ short As[128 * 32];
  const int t    = threadIdx.x;
  const int w    = t >> 6;
  const int lane = t & 63;
  const int lr   = lane & 15;
  const int g    = lane >> 4;
  const int bm   = blockIdx.x * 128;

  f32x4 acc[2][4] = {};

  for (int k0 = 0; k0 < NHID; k0 += 32) {
#pragma unroll
    for (int p = 0; p < 2; ++p) {
      const int gran = p * 256 + t;
      const int row  = gran >> 2;
      const int kc   = (gran & 3) << 3;
      const int grow = bm + row;
      bf16x8 av = {};
      if (grow < M) av = *(const bf16x8*)(A + (size_t)grow * NHID + k0 + kc);
      *(bf16x8*)(&As[gran * 8]) = av;
    }
    __syncthreads();

    bf16x8 bfr[4];
#pragma unroll
    for (int n = 0; n < 4; ++n) {
      const int col = n * 16 + lr;
      bfr[n] = *(const bf16x8*)(BT + (size_t)col * NHID + k0 + g * 8);
    }
#pragma unroll
    for (int m = 0; m < 2; ++m) {
      const bf16x8 af = *(const bf16x8*)(&As[(w * 32 + m * 16 + lr) * 32 + g * 8]);
#pragma unroll
      for (int n = 0; n < 4; ++n)
        acc[m][n] = __builtin_amdgcn_mfma_f32_16x16x32_bf16(af, bfr[n], acc[m][n], 0, 0, 0);
    }
    __syncthreads();
  }

#pragma unroll
  for (int m = 0; m < 2; ++m) {
#pragma unroll
    for (int r = 0; r < 4; ++r) {
      const int row = bm + w * 32 + m * 16 + g * 4 + r;
      if (row < M) {
#pragma unroll
        for (int n = 0; n < 4; ++n) {
          const int col = n * 16 + lr;
          C[(size_t)row * NCLASS + col] = f2bf(acc[m][n][r]);
        }
      }
    }
  }
}

// ---------------- atomic-free CSR build: chunk x window counting sort
// partial[a][c][r] : per-(adjacency, edge-chunk) row counts -> later in-place
// converted to per-(chunk,row) start offsets (stable counting sort).

// grid (CH, NWIN, 2): LDS histogram per (chunk, window), non-atomic global write
__global__ __launch_bounds__(256)
void hist_win_k(const int* __restrict__ r1, const int* __restrict__ r2,
                int* __restrict__ partial, int M, int E1, int E2) {
  __shared__ int hist[WBINS];
  const int c = blockIdx.x, w = blockIdx.y, a = blockIdx.z;
  const int* rows = a ? r2 : r1;
  const int E = a ? E2 : E1;
  const int rlo = w * WBINS;
  const int rhi = min(M, rlo + WBINS);
  for (int b = threadIdx.x; b < WBINS; b += 256) hist[b] = 0;
  __syncthreads();
  const int csz = (E + CH - 1) / CH;
  const int e0 = c * csz, e1 = min(E, e0 + csz);
  for (int i = e0 + threadIdx.x; i < e1; i += 256) {
    const int r = rows[i];
    if (r >= rlo && r < rhi) atomicAdd(&hist[r - rlo], 1);
  }
  __syncthreads();
  int* dst = partial + (size_t)(a * CH + c) * M;
  for (int b = threadIdx.x; b < rhi - rlo; b += 256) dst[rlo + b] = hist[b];
}

// grid ((M+255)/256, 2): cnt[a][r] = sum_c partial[a][c][r]
__global__ __launch_bounds__(256)
void merge_cnt_k(const int* __restrict__ partial, int* __restrict__ cnt, int M) {
  const int r = blockIdx.x * 256 + threadIdx.x;
  const int a = blockIdx.y;
  if (r >= M) return;
  int s = 0;
#pragma unroll 4
  for (int c = 0; c < CH; ++c) s += partial[(size_t)(a * CH + c) * M + r];
  cnt[a * M + r] = s;
}

// grid (G, 2)
__global__ __launch_bounds__(256)
void scan_partial_k(const int* __restrict__ cnt, int* __restrict__ partial, int M) {
  __shared__ int red[256];
  const int b = blockIdx.x, t = threadIdx.x, seg = blockIdx.y;
  const int* cs = cnt + (size_t)seg * M;
  const int base = b * 1024 + t * 4;
  int s = 0;
#pragma unroll
  for (int i = 0; i < 4; ++i) { const int idx = base + i; if (idx < M) s += cs[idx]; }
  red[t] = s; __syncthreads();
  for (int off = 128; off; off >>= 1) { if (t < off) red[t] += red[t + off]; __syncthreads(); }
  if (t == 0) partial[seg * 256 + b] = red[0];
}

// grid (2): one block per segment
__global__ __launch_bounds__(256)
void scan_offsets_k(int* __restrict__ partial, int G) {
  __shared__ int buf[256];
  const int t = threadIdx.x;
  int* ps = partial + blockIdx.x * 256;
  const int v = (t < G) ? ps[t] : 0;
  buf[t] = v; __syncthreads();
  for (int off = 1; off < 256; off <<= 1) {
    const int x = (t >= off) ? buf[t - off] : 0;
    __syncthreads();
    buf[t] += x;
    __syncthreads();
  }
  if (t < G) ps[t] = buf[t] - v;
}

// grid (G, 2)
__global__ __launch_bounds__(256)
void scan_final_k(const int* __restrict__ cnt, const int* __restrict__ partial,
                  int* __restrict__ row_ptr, int M, int E1, int E2) {
  __shared__ int red[256];
  const int b = blockIdx.x, t = threadIdx.x, seg = blockIdx.y;
  const int* cs   = cnt + (size_t)seg * M;
  int* rps        = row_ptr + (size_t)seg * (M + 1);
  const int E     = seg == 0 ? E1 : E2;
  const int base  = b * 1024 + t * 4;
  int v[4]; int s = 0;
#pragma unroll
  for (int i = 0; i < 4; ++i) { const int idx = base + i; v[i] = (idx < M) ? cs[idx] : 0; s += v[i]; }
  red[t] = s; __syncthreads();
  for (int off = 1; off < 256; off <<= 1) {
    const int x = (t >= off) ? red[t - off] : 0;
    __syncthreads();
    red[t] += x;
    __syncthreads();
  }
  int excl = red[t] - s + partial[seg * 256 + b];
#pragma unroll
  for (int i = 0; i < 4; ++i) {
    const int idx = base + i;
    if (idx < M) { rps[idx] = excl; excl += v[i]; }
  }
  if (b == 0 && t == 0) rps[M] = E;
}

// grid ((M+255)/256, 2): in-place partial counts -> start offsets
__global__ __launch_bounds__(256)
void base_k(int* __restrict__ partial, const int* __restrict__ row_ptr, int M) {
  const int r = blockIdx.x * 256 + threadIdx.x;
  const int a = blockIdx.y;
  if (r >= M) return;
  int run = row_ptr[(size_t)a * (M + 1) + r];
#pragma unroll 4
  for (int c = 0; c < CH; ++c) {
    const size_t idx = (size_t)(a * CH + c) * M + r;
    const int tv = partial[idx];
    partial[idx] = run;
    run += tv;
  }
}

// grid (CH, NWIN, 2): scatter via LDS cursors (no global atomics)
__global__ __launch_bounds__(256)
void scatter_win2_k(const int* __restrict__ r1, const int* __restrict__ c1, const float* __restrict__ v1,
                    const int* __restrict__ r2, const int* __restrict__ c2, const float* __restrict__ v2,
                    const int* __restrict__ partial,
                    unsigned long long* __restrict__ ecv1, unsigned long long* __restrict__ ecv2,
                    int M, int E1, int E2) {
  __shared__ int cur[WBINS];
  const int c = blockIdx.x, w = blockIdx.y, a = blockIdx.z;
  const int* rows = a ? r2 : r1;
  const int* cols = a ? c2 : c1;
  const float* vals = a ? v2 : v1;
  unsigned long long* ecv = a ? ecv2 : ecv1;
  const int E = a ? E2 : E1;
  const int rlo = w * WBINS;
  const int rhi = min(M, rlo + WBINS);
  const int* bs = partial + (size_t)(a * CH + c) * M;
  for (int b = threadIdx.x; b < rhi - rlo; b += 256) cur[b] = bs[rlo + b];
  __syncthreads();
  const int csz = (E + CH - 1) / CH;
  const int e0 = c * csz, e1 = min(E, e0 + csz);
  for (int i = e0 + threadIdx.x; i < e1; i += 256) {
    const int r = rows[i];
    if (r >= rlo && r < rhi) {
      const int pos = atomicAdd(&cur[r - rlo], 1);
      ecv[pos] = ((unsigned long long)__builtin_bit_cast(unsigned, vals[i]) << 32) | (unsigned)cols[i];
    }
  }
}

// ---------------- CSR SpMM D=256 bf16: one wave/row, packed payload, fused bias+relu
__global__ __launch_bounds__(256)
void spmm_csr_d256_bf(const int* __restrict__ rp, const unsigned long long* __restrict__ ecv,
                      const unsigned short* __restrict__ dense,
                      const float* __restrict__ bias, unsigned short* __restrict__ out, int M) {
  const int wid = (blockIdx.x * 256 + threadIdx.x) >> 6;
  if (wid >= M) return;
  const int lane = threadIdx.x & 63;
  const int d4 = lane << 2;
  const int start = rp[wid], end = rp[wid + 1];
  float4 acc[2];
  acc[0] = *(const float4*)(bias + d4);
  acc[1] = make_float4(0.f, 0.f, 0.f, 0.f);
  for (int j0 = start; j0 < end; j0 += 64) {
    const int jm = min(64, end - j0);
    const int jr = (jm + 7) & ~7;
    const unsigned long long pk = (lane < jm) ? ecv[j0 + lane] : 0ULL;
    for (int kk = 0; kk < jr; kk += 8) {
#pragma unroll
      for (int u = 0; u < 8; ++u) {
        const unsigned long long pp = __shfl(pk, kk + u);
        const int   cc = (int)(unsigned)pp;
        const float vv = __builtin_bit_cast(float, (unsigned)(pp >> 32));
        const ushort4 gg = *(const ushort4*)(dense + (size_t)cc * NHID + d4);
        acc[u & 1].x += vv * bfu(gg.x); acc[u & 1].y += vv * bfu(gg.y);
        acc[u & 1].z += vv * bfu(gg.z); acc[u & 1].w += vv * bfu(gg.w);
      }
    }
  }
  ushort4 o;
  o.x = f2bf(fmaxf(acc[0].x + acc[1].x, 0.f)); o.y = f2bf(fmaxf(acc[0].y + acc[1].y, 0.f));
  o.z = f2bf(fmaxf(acc[0].z + acc[1].z, 0.f)); o.w = f2bf(fmaxf(acc[0].w + acc[1].w, 0.f));
  *(ushort4*)(out + (size_t)wid * NHID + d4) = o;
}

// ---------------- CSR SpMM D=64 bf16: one wave/row, packed payload, fused bias+log_softmax
__global__ __launch_bounds__(256)
void spmm_csr_d64_lsm_bf(const int* __restrict__ rp, const unsigned long long* __restrict__ ecv,
                         const unsigned short* __restrict__ dense,
                         const float* __restrict__ bias, float* __restrict__ out, int M) {
  const int wid = (blockIdx.x * 256 + threadIdx.x) >> 6;
  if (wid >= M) return;
  const int lane = threadIdx.x & 63;
  const int start = rp[wid], end = rp[wid + 1];
  float acc0 = bias[lane], acc1 = 0.f;
  for (int j0 = start; j0 < end; j0 += 64) {
    const int jm = min(64, end - j0);
    const int jr = (jm + 7) & ~7;
    const unsigned long long pk = (lane < jm) ? ecv[j0 + lane] : 0ULL;
    for (int kk = 0; kk < jr; kk += 8) {
#pragma unroll
      for (int u = 0; u < 8; ++u) {
        const unsigned long long pp = __shfl(pk, kk + u);
        const int   cc = (int)(unsigned)pp;
        const float vv = __builtin_bit_cast(float, (unsigned)(pp >> 32));
        const float gv = bfu(dense[(size_t)cc * NCLASS + lane]);
        if (u & 1) acc1 += vv * gv; else acc0 += vv * gv;
      }
    }
  }
  const float acc = acc0 + acc1;
  float m = acc;
#pragma unroll
  for (int off = 32; off; off >>= 1) m = fmaxf(m, __shfl_xor(m, off));
  const float e = __expf(acc - m);
  float s = e;
#pragma unroll
  for (int off = 32; off; off >>= 1) s += __shfl_xor(s, off);
  out[(size_t)wid * NCLASS + lane] = acc - m - __logf(s);
}

// ---------------- launch
static inline size_t align256(size_t x) { return (x + 255) & ~(size_t)255; }

extern "C" void kernel_launch(void* const* d_in, const int* in_sizes, int n_in,
                              void* d_out, int out_size, void* d_ws, size_t ws_size,
                              hipStream_t stream) {
  const float* x   = (const float*)d_in[0];
  const int*   a1r = (const int*)d_in[1];
  const int*   a1c = (const int*)d_in[2];
  const float* a1v = (const float*)d_in[3];
  const int*   a2r = (const int*)d_in[4];
  const int*   a2c = (const int*)d_in[5];
  const float* a2v = (const float*)d_in[6];
  const float* W1  = (const float*)d_in[7];
  const float* b1  = (const float*)d_in[8];
  const float* W2  = (const float*)d_in[9];
  const float* b2  = (const float*)d_in[10];
  float* out = (float*)d_out;

  const int M  = in_sizes[0] / NFEAT;
  const int E1 = in_sizes[1];
  const int E2 = in_sizes[4];
  const int G    = (M + 1023) / 1024;
  const int NWIN = (M + WBINS - 1) / WBINS;

  char* p = (char*)d_ws;
  unsigned short* s1  = (unsigned short*)p;        p += align256((size_t)M * NHID * sizeof(short));
  unsigned short* h   = (unsigned short*)p;        p += align256((size_t)M * NHID * sizeof(short));
  unsigned short* s2  = (unsigned short*)p;        p += align256((size_t)M * NCLASS * sizeof(short));
  short* W1T          = (short*)p;                 p += align256((size_t)NFEAT * NHID * sizeof(short));
  short* W2T          = (short*)p;                 p += align256((size_t)NHID * NCLASS * sizeof(short));
  int*   partial      = (int*)p;                   p += align256((size_t)2 * CH * M * sizeof(int));
  int*   cnt          = (int*)p;                   p += align256((size_t)2 * M * sizeof(int));
  int*   row_ptr      = (int*)p;                   p += align256((size_t)2 * (M + 1) * sizeof(int));
  int*   spartial     = (int*)p;                   p += align256(512 * sizeof(int));
  unsigned long long* ecv1 = (unsigned long long*)p; p += align256((size_t)E1 * 8);
  unsigned long long* ecv2 = (unsigned long long*)p; p += align256((size_t)E2 * 8);

  const int blkRow = (M * 64 + 255) / 256;
  const int blkG   = (M + 127) / 128;
  const int blkM2  = (M + 255) / 256;

  // 0) weight conversions
  convert_w12<<<(512 * 256 + 255) / 256, 256, 0, stream>>>(W1, W1T, W2, W2T);
  // 1) atomic-free CSR build for both adjacencies
  {
    dim3 gH(CH, NWIN, 2);
    hist_win_k<<<gH, 256, 0, stream>>>(a1r, a2r, partial, M, E1, E2);
    dim3 gM(blkM2, 2);
    merge_cnt_k<<<gM, 256, 0, stream>>>(partial, cnt, M);
    dim3 gP(G, 2);
    scan_partial_k<<<gP, 256, 0, stream>>>(cnt, spartial, M);
    scan_offsets_k<<<2, 256, 0, stream>>>(spartial, G);
    scan_final_k<<<gP, 256, 0, stream>>>(cnt, spartial, row_ptr, M, E1, E2);
    base_k<<<gM, 256, 0, stream>>>(partial, row_ptr, M);
    scatter_win2_k<<<gH, 256, 0, stream>>>(a1r, a1c, a1v, a2r, a2c, a2v,
                                           partial, ecv1, ecv2, M, E1, E2);
  }
  // 2) support1 = bf16(x @ W1)
  gemm1_mfma<<<blkG, 256, 0, stream>>>(x, W1T, s1, M);
  // 3) h = bf16(relu(adj1 @ support1 + b1))
  spmm_csr_d256_bf<<<blkRow, 256, 0, stream>>>(row_ptr, ecv1, s1, b1, h, M);
  // 4) support2 = bf16(h @ W2)
  gemm2_mfma<<<blkG, 256, 0, stream>>>(h, W2T, s2, M);
  // 5) out = log_softmax(adj2 @ support2 + b2)
  spmm_csr_d64_lsm_bf<<<blkRow, 256, 0, stream>>>(row_ptr + (M + 1), ecv2, s2, b2, out, M);
}

// Round 7
// 740.632 us; speedup vs baseline: 1.4685x; 1.4685x over previous
//
#include <hip/hip_runtime.h>
#include <cstdint>

#define NFEAT 512
#define NHID 256
#define NCLASS 64
#define RPB 256          // rows per bucket (8-bit row_local)
#define MAXBUK 512       // static LDS sizing; M <= 131072
#define TEDG 8192        // edges per pass-1 tile

typedef __attribute__((ext_vector_type(8))) short bf16x8;
typedef __attribute__((ext_vector_type(4))) float f32x4;

__device__ __forceinline__ unsigned short f2bf(float f) {
  unsigned u = __builtin_bit_cast(unsigned, f);
  u = (u + 0x7FFF + ((u >> 16) & 1)) >> 16;   // RNE
  return (unsigned short)u;
}
__device__ __forceinline__ float bfu(unsigned short u) {
  return __builtin_bit_cast(float, (unsigned)u << 16);
}

// ---------------- weight conversion (fused, once per call, tiny)
__global__ __launch_bounds__(256)
void convert_w12(const float* __restrict__ W1, short* __restrict__ W1T,
                 const float* __restrict__ W2, short* __restrict__ W2T) {
  const int idx = blockIdx.x * 256 + threadIdx.x;
  if (idx < 512 * 256) {
    const int k = idx >> 8, n = idx & 255;
    W1T[n * 512 + k] = (short)f2bf(W1[idx]);
  }
  if (idx < 256 * 64) {
    const int k = idx >> 6, n = idx & 63;
    W2T[n * 256 + k] = (short)f2bf(W2[idx]);
  }
}

// ---------------- GEMM1: C[M][256](bf16) = A[M][512](fp32) @ W1, B = W1T [256][512] bf16
__global__ __launch_bounds__(256)
void gemm1_mfma(const float* __restrict__ A, const short* __restrict__ BT,
                unsigned short* __restrict__ C, int M) {
  __shared__ short As[128 * 32];            // 8 KB
  const int t    = threadIdx.x;
  const int w    = t >> 6;
  const int lane = t & 63;
  const int lr   = lane & 15;
  const int g    = lane >> 4;
  const int bm   = blockIdx.x * 128;

  f32x4 acc[8][4] = {};

  for (int k0 = 0; k0 < NFEAT; k0 += 32) {
#pragma unroll
    for (int p = 0; p < 2; ++p) {
      const int gran = p * 256 + t;
      const int row  = gran >> 2;
      const int kc   = (gran & 3) << 3;
      const int grow = bm + row;
      float4 f0 = make_float4(0.f, 0.f, 0.f, 0.f), f1 = f0;
      if (grow < M) {
        const float* src = A + (size_t)grow * NFEAT + k0 + kc;
        f0 = *(const float4*)(src);
        f1 = *(const float4*)(src + 4);
      }
      union { bf16x8 v; unsigned short u[8]; } pk;
      pk.u[0] = f2bf(f0.x); pk.u[1] = f2bf(f0.y); pk.u[2] = f2bf(f0.z); pk.u[3] = f2bf(f0.w);
      pk.u[4] = f2bf(f1.x); pk.u[5] = f2bf(f1.y); pk.u[6] = f2bf(f1.z); pk.u[7] = f2bf(f1.w);
      *(bf16x8*)(&As[gran * 8]) = pk.v;
    }
    __syncthreads();

    bf16x8 bfr[4];
#pragma unroll
    for (int n = 0; n < 4; ++n) {
      const int col = w * 64 + n * 16 + lr;
      bfr[n] = *(const bf16x8*)(BT + (size_t)col * NFEAT + k0 + g * 8);
    }
#pragma unroll
    for (int m = 0; m < 8; ++m) {
      const bf16x8 af = *(const bf16x8*)(&As[(m * 16 + lr) * 32 + g * 8]);
#pragma unroll
      for (int n = 0; n < 4; ++n)
        acc[m][n] = __builtin_amdgcn_mfma_f32_16x16x32_bf16(af, bfr[n], acc[m][n], 0, 0, 0);
    }
    __syncthreads();
  }

#pragma unroll
  for (int m = 0; m < 8; ++m) {
#pragma unroll
    for (int r = 0; r < 4; ++r) {
      const int row = bm + m * 16 + g * 4 + r;
      if (row < M) {
#pragma unroll
        for (int n = 0; n < 4; ++n) {
          const int col = w * 64 + n * 16 + lr;
          C[(size_t)row * NHID + col] = f2bf(acc[m][n][r]);
        }
      }
    }
  }
}

// ---------------- GEMM2: C[M][64](bf16) = A[M][256](bf16) @ W2, B = W2T [64][256] bf16
__global__ __launch_bounds__(256)
void gemm2_mfma(const unsigned short* __restrict__ A, const short* __restrict__ BT,
                unsigned short* __restrict__ C, int M) {
  __shared__ short As[128 * 32];
  const int t    = threadIdx.x;
  const int w    = t >> 6;
  const int lane = t & 63;
  const int lr   = lane & 15;
  const int g    = lane >> 4;
  const int bm   = blockIdx.x * 128;

  f32x4 acc[2][4] = {};

  for (int k0 = 0; k0 < NHID; k0 += 32) {
#pragma unroll
    for (int p = 0; p < 2; ++p) {
      const int gran = p * 256 + t;
      const int row  = gran >> 2;
      const int kc   = (gran & 3) << 3;
      const int grow = bm + row;
      bf16x8 av = {};
      if (grow < M) av = *(const bf16x8*)(A + (size_t)grow * NHID + k0 + kc);
      *(bf16x8*)(&As[gran * 8]) = av;
    }
    __syncthreads();

    bf16x8 bfr[4];
#pragma unroll
    for (int n = 0; n < 4; ++n) {
      const int col = n * 16 + lr;
      bfr[n] = *(const bf16x8*)(BT + (size_t)col * NHID + k0 + g * 8);
    }
#pragma unroll
    for (int m = 0; m < 2; ++m) {
      const bf16x8 af = *(const bf16x8*)(&As[(w * 32 + m * 16 + lr) * 32 + g * 8]);
#pragma unroll
      for (int n = 0; n < 4; ++n)
        acc[m][n] = __builtin_amdgcn_mfma_f32_16x16x32_bf16(af, bfr[n], acc[m][n], 0, 0, 0);
    }
    __syncthreads();
  }

#pragma unroll
  for (int m = 0; m < 2; ++m) {
#pragma unroll
    for (int r = 0; r < 4; ++r) {
      const int row = bm + w * 32 + m * 16 + g * 4 + r;
      if (row < M) {
#pragma unroll
        for (int n = 0; n < 4; ++n) {
          const int col = n * 16 + lr;
          C[(size_t)row * NCLASS + col] = f2bf(acc[m][n][r]);
        }
      }
    }
  }
}

// ================= atomic-light 2-pass bucket CSR build =================

__global__ __launch_bounds__(256)
void zero_small_k(int* __restrict__ p, int n) {
  const int i = blockIdx.x * 256 + threadIdx.x;
  if (i < n) p[i] = 0;
}

// grid (NB0, 2): per-block LDS bucket histogram, merged atomically (few atomics)
__global__ __launch_bounds__(256)
void bucket_hist_k(const int* __restrict__ r1, const int* __restrict__ r2,
                   int* __restrict__ bkt_cnt, int nbuk, int E1, int E2) {
  __shared__ int hist[MAXBUK];
  const int a = blockIdx.y;
  const int* rows = a ? r2 : r1;
  const int E = a ? E2 : E1;
  for (int b = threadIdx.x; b < MAXBUK; b += 256) hist[b] = 0;
  __syncthreads();
  const int nb = gridDim.x;
  const int csz = (E + nb - 1) / nb;
  const int e0 = blockIdx.x * csz, e1 = min(E, e0 + csz);
  for (int i = e0 + threadIdx.x; i < e1; i += 256)
    atomicAdd(&hist[rows[i] >> 8], 1);
  __syncthreads();
  for (int b = threadIdx.x; b < nbuk; b += 256) {
    const int h = hist[b];
    if (h) atomicAdd(&bkt_cnt[a * nbuk + b], h);
  }
}

// grid (2): exclusive scan over nbuk bucket counts -> base, tail; row_ptr[M]=E
__global__ __launch_bounds__(256)
void bucket_scan_k(const int* __restrict__ bkt_cnt, int* __restrict__ base,
                   int* __restrict__ tail, int* __restrict__ row_ptr,
                   int nbuk, int M, int E1, int E2) {
  __shared__ int pair[256];
  const int a = blockIdx.x;
  const int E = a ? E2 : E1;
  const int t = threadIdx.x;
  const int b0 = t * 2, b1 = t * 2 + 1;
  const int v0 = (b0 < nbuk) ? bkt_cnt[a * nbuk + b0] : 0;
  const int v1 = (b1 < nbuk) ? bkt_cnt[a * nbuk + b1] : 0;
  pair[t] = v0 + v1;
  __syncthreads();
  for (int off = 1; off < 256; off <<= 1) {
    const int x = (t >= off) ? pair[t - off] : 0;
    __syncthreads();
    pair[t] += x;
    __syncthreads();
  }
  const int excl = pair[t] - (v0 + v1);
  if (b0 < nbuk) { base[a * (nbuk + 1) + b0] = excl;      tail[a * nbuk + b0] = excl; }
  if (b1 < nbuk) { base[a * (nbuk + 1) + b1] = excl + v0; tail[a * nbuk + b1] = excl + v0; }
  if (t == 0) { base[a * (nbuk + 1) + nbuk] = E; row_ptr[a * (M + 1) + M] = E; }
}

// grid (ntiles, 2): tile-reserved dense bucket append.
// payload pack: val(32) | row_local(8, bits 17-24) | col(17, bits 0-16)
__global__ __launch_bounds__(256)
void bucket_append_k(const int* __restrict__ r1, const int* __restrict__ c1, const float* __restrict__ v1,
                     const int* __restrict__ r2, const int* __restrict__ c2, const float* __restrict__ v2,
                     int* __restrict__ tail,
                     unsigned long long* __restrict__ ecvP1, unsigned long long* __restrict__ ecvP2,
                     int nbuk, int E1, int E2) {
  __shared__ int cnt[MAXBUK], rsv[MAXBUK], cur[MAXBUK];
  const int a = blockIdx.y;
  const int* rows = a ? r2 : r1;
  const int* cols = a ? c2 : c1;
  const float* vals = a ? v2 : v1;
  unsigned long long* ecvP = a ? ecvP2 : ecvP1;
  const int E = a ? E2 : E1;
  const int e0 = blockIdx.x * TEDG;
  if (e0 >= E) return;
  const int e1 = min(E, e0 + TEDG);
  for (int b = threadIdx.x; b < MAXBUK; b += 256) { cnt[b] = 0; cur[b] = 0; }
  __syncthreads();
  for (int i = e0 + threadIdx.x; i < e1; i += 256)
    atomicAdd(&cnt[rows[i] >> 8], 1);
  __syncthreads();
  for (int b = threadIdx.x; b < nbuk; b += 256) {
    const int c = cnt[b];
    rsv[b] = c ? atomicAdd(&tail[a * nbuk + b], c) : 0;
  }
  __syncthreads();
  for (int i = e0 + threadIdx.x; i < e1; i += 256) {
    const int r = rows[i];
    const int b = r >> 8;
    const int pos = rsv[b] + atomicAdd(&cur[b], 1);
    const unsigned long long pk =
        ((unsigned long long)__builtin_bit_cast(unsigned, vals[i]) << 32)
        | ((unsigned)(r & 255) << 17) | (unsigned)cols[i];
    ecvP[pos] = pk;
  }
}

// grid (nbuk, 2): in-bucket counting sort -> final CSR payload + row_ptr
__global__ __launch_bounds__(256)
void bucket_csr_k(const unsigned long long* __restrict__ ecvP1,
                  const unsigned long long* __restrict__ ecvP2,
                  const int* __restrict__ base, int* __restrict__ row_ptr,
                  unsigned long long* __restrict__ ecv1, unsigned long long* __restrict__ ecv2,
                  int nbuk, int M) {
  __shared__ int hist[RPB], excl[RPB], cur[RPB];
  const int b = blockIdx.x, a = blockIdx.y;
  const unsigned long long* src = a ? ecvP2 : ecvP1;
  unsigned long long* dst = a ? ecv2 : ecv1;
  const int s = base[a * (nbuk + 1) + b];
  const int e = base[a * (nbuk + 1) + b + 1];
  const int t = threadIdx.x;
  hist[t] = 0;
  __syncthreads();
  for (int i = s + t; i < e; i += 256) {
    const unsigned lo = (unsigned)src[i];
    atomicAdd(&hist[(lo >> 17) & 255], 1);
  }
  __syncthreads();
  const int v = hist[t];
  excl[t] = v;
  __syncthreads();
  for (int off = 1; off < 256; off <<= 1) {
    const int x = (t >= off) ? excl[t - off] : 0;
    __syncthreads();
    excl[t] += x;
    __syncthreads();
  }
  const int ex = excl[t] - v;          // exclusive
  const int r = b * RPB + t;
  if (r < M) row_ptr[a * (M + 1) + r] = s + ex;
  cur[t] = s + ex;
  __syncthreads();
  for (int i = s + t; i < e; i += 256) {
    const unsigned long long pk = src[i];
    const unsigned lo = (unsigned)pk;
    const int rl = (lo >> 17) & 255;
    const int pos = atomicAdd(&cur[rl], 1);
    dst[pos] = (pk & 0xFFFFFFFF00000000ULL) | (lo & 0x1FFFFu);
  }
}

// ---------------- CSR SpMM D=256 bf16: one wave/row, packed payload, fused bias+relu
__global__ __launch_bounds__(256)
void spmm_csr_d256_bf(const int* __restrict__ rp, const unsigned long long* __restrict__ ecv,
                      const unsigned short* __restrict__ dense,
                      const float* __restrict__ bias, unsigned short* __restrict__ out, int M) {
  const int wid = (blockIdx.x * 256 + threadIdx.x) >> 6;
  if (wid >= M) return;
  const int lane = threadIdx.x & 63;
  const int d4 = lane << 2;
  const int start = rp[wid], end = rp[wid + 1];
  float4 acc[2];
  acc[0] = *(const float4*)(bias + d4);
  acc[1] = make_float4(0.f, 0.f, 0.f, 0.f);
  for (int j0 = start; j0 < end; j0 += 64) {
    const int jm = min(64, end - j0);
    const int jr = (jm + 7) & ~7;
    const unsigned long long pk = (lane < jm) ? ecv[j0 + lane] : 0ULL;
    for (int kk = 0; kk < jr; kk += 8) {
#pragma unroll
      for (int u = 0; u < 8; ++u) {
        const unsigned long long pp = __shfl(pk, kk + u);
        const int   cc = (int)(unsigned)pp & 0x1FFFF;
        const float vv = __builtin_bit_cast(float, (unsigned)(pp >> 32));
        const ushort4 gg = *(const ushort4*)(dense + (size_t)cc * NHID + d4);
        acc[u & 1].x += vv * bfu(gg.x); acc[u & 1].y += vv * bfu(gg.y);
        acc[u & 1].z += vv * bfu(gg.z); acc[u & 1].w += vv * bfu(gg.w);
      }
    }
  }
  ushort4 o;
  o.x = f2bf(fmaxf(acc[0].x + acc[1].x, 0.f)); o.y = f2bf(fmaxf(acc[0].y + acc[1].y, 0.f));
  o.z = f2bf(fmaxf(acc[0].z + acc[1].z, 0.f)); o.w = f2bf(fmaxf(acc[0].w + acc[1].w, 0.f));
  *(ushort4*)(out + (size_t)wid * NHID + d4) = o;
}

// ---------------- CSR SpMM D=64 bf16: one wave/row, packed payload, fused bias+log_softmax
__global__ __launch_bounds__(256)
void spmm_csr_d64_lsm_bf(const int* __restrict__ rp, const unsigned long long* __restrict__ ecv,
                         const unsigned short* __restrict__ dense,
                         const float* __restrict__ bias, float* __restrict__ out, int M) {
  const int wid = (blockIdx.x * 256 + threadIdx.x) >> 6;
  if (wid >= M) return;
  const int lane = threadIdx.x & 63;
  const int start = rp[wid], end = rp[wid + 1];
  float acc0 = bias[lane], acc1 = 0.f;
  for (int j0 = start; j0 < end; j0 += 64) {
    const int jm = min(64, end - j0);
    const int jr = (jm + 7) & ~7;
    const unsigned long long pk = (lane < jm) ? ecv[j0 + lane] : 0ULL;
    for (int kk = 0; kk < jr; kk += 8) {
#pragma unroll
      for (int u = 0; u < 8; ++u) {
        const unsigned long long pp = __shfl(pk, kk + u);
        const int   cc = (int)(unsigned)pp & 0x1FFFF;
        const float vv = __builtin_bit_cast(float, (unsigned)(pp >> 32));
        const float gv = bfu(dense[(size_t)cc * NCLASS + lane]);
        if (u & 1) acc1 += vv * gv; else acc0 += vv * gv;
      }
    }
  }
  const float acc = acc0 + acc1;
  float m = acc;
#pragma unroll
  for (int off = 32; off; off >>= 1) m = fmaxf(m, __shfl_xor(m, off));
  const float e = __expf(acc - m);
  float s = e;
#pragma unroll
  for (int off = 32; off; off >>= 1) s += __shfl_xor(s, off);
  out[(size_t)wid * NCLASS + lane] = acc - m - __logf(s);
}

// ---------------- launch
static inline size_t align256(size_t x) { return (x + 255) & ~(size_t)255; }

extern "C" void kernel_launch(void* const* d_in, const int* in_sizes, int n_in,
                              void* d_out, int out_size, void* d_ws, size_t ws_size,
                              hipStream_t stream) {
  const float* x   = (const float*)d_in[0];
  const int*   a1r = (const int*)d_in[1];
  const int*   a1c = (const int*)d_in[2];
  const float* a1v = (const float*)d_in[3];
  const int*   a2r = (const int*)d_in[4];
  const int*   a2c = (const int*)d_in[5];
  const float* a2v = (const float*)d_in[6];
  const float* W1  = (const float*)d_in[7];
  const float* b1  = (const float*)d_in[8];
  const float* W2  = (const float*)d_in[9];
  const float* b2  = (const float*)d_in[10];
  float* out = (float*)d_out;

  const int M  = in_sizes[0] / NFEAT;
  const int E1 = in_sizes[1];
  const int E2 = in_sizes[4];
  const int Emax = (E1 > E2) ? E1 : E2;
  const int nbuk = (M + RPB - 1) / RPB;      // 391 for M=100000
  const int ntiles = (Emax + TEDG - 1) / TEDG;

  // ecvP (pass-1 scratch) aliases s1: gemm1 writes s1 only after bucket_csr_k.
  char* p = (char*)d_ws;
  char* regionA       = p;                          p += align256((size_t)M * NHID * sizeof(short)); // 51.2MB
  unsigned short* s1  = (unsigned short*)regionA;
  unsigned long long* ecvP1 = (unsigned long long*)regionA;
  unsigned long long* ecvP2 = (unsigned long long*)(regionA + align256((size_t)E1 * 8));
  unsigned short* h   = (unsigned short*)p;         p += align256((size_t)M * NHID * sizeof(short));
  unsigned short* s2  = (unsigned short*)p;         p += align256((size_t)M * NCLASS * sizeof(short));
  short* W1T          = (short*)p;                  p += align256((size_t)NFEAT * NHID * sizeof(short));
  short* W2T          = (short*)p;                  p += align256((size_t)NHID * NCLASS * sizeof(short));
  unsigned long long* ecv1 = (unsigned long long*)p; p += align256((size_t)E1 * 8);
  unsigned long long* ecv2 = (unsigned long long*)p; p += align256((size_t)E2 * 8);
  int*   row_ptr      = (int*)p;                    p += align256((size_t)2 * (M + 1) * sizeof(int));
  int*   bkt_cnt      = (int*)p;                    p += align256((size_t)2 * nbuk * sizeof(int));
  int*   bkt_base     = (int*)p;                    p += align256((size_t)2 * (nbuk + 1) * sizeof(int));
  int*   bkt_tail     = (int*)p;                    p += align256((size_t)2 * nbuk * sizeof(int));

  const int blkRow = (M * 64 + 255) / 256;
  const int blkG   = (M + 127) / 128;

  // 0) weight conversions
  convert_w12<<<(512 * 256 + 255) / 256, 256, 0, stream>>>(W1, W1T, W2, W2T);
  // 1) bucket-sort CSR build (both adjacencies)
  zero_small_k<<<(2 * nbuk + 255) / 256, 256, 0, stream>>>(bkt_cnt, 2 * nbuk);
  {
    dim3 gH(256, 2);
    bucket_hist_k<<<gH, 256, 0, stream>>>(a1r, a2r, bkt_cnt, nbuk, E1, E2);
    bucket_scan_k<<<2, 256, 0, stream>>>(bkt_cnt, bkt_base, bkt_tail, row_ptr, nbuk, M, E1, E2);
    dim3 gA(ntiles, 2);
    bucket_append_k<<<gA, 256, 0, stream>>>(a1r, a1c, a1v, a2r, a2c, a2v,
                                            bkt_tail, ecvP1, ecvP2, nbuk, E1, E2);
    dim3 gC(nbuk, 2);
    bucket_csr_k<<<gC, 256, 0, stream>>>(ecvP1, ecvP2, bkt_base, row_ptr, ecv1, ecv2, nbuk, M);
  }
  // 2) support1 = bf16(x @ W1)  (overwrites ecvP scratch)
  gemm1_mfma<<<blkG, 256, 0, stream>>>(x, W1T, s1, M);
  // 3) h = bf16(relu(adj1 @ support1 + b1))
  spmm_csr_d256_bf<<<blkRow, 256, 0, stream>>>(row_ptr, ecv1, s1, b1, h, M);
  // 4) support2 = bf16(h @ W2)
  gemm2_mfma<<<blkG, 256, 0, stream>>>(h, W2T, s2, M);
  // 5) out = log_softmax(adj2 @ support2 + b2)
  spmm_csr_d64_lsm_bf<<<blkRow, 256, 0, stream>>>(row_ptr + (M + 1), ecv2, s2, b2, out, M);
}